// Round 3
// baseline (129.517 us; speedup 1.0000x reference)
//
#include <hip/hip_runtime.h>
#include <cmath>

// Conductance-based LIF scan: T=512 steps, N=65536 neurons.
// One thread per neuron (1024 waves = 4/CU -> occupancy capped at 12.5%),
// so HBM latency is hidden with ILP: register double-buffered prefetch of
// PFD=16 steps (3 floats/step).
//
// R3 change: decay exp computed with f32 expf (ocml, <=1 ulp) instead of
// double exp. darg in [-0.16,-0.05] -> per-step v perturbation ~1e-8,
// accumulated ~1e-6, far under the 0.0039 margin R2 measured. All other
// arithmetic unchanged: __f{mul,add,sub}_rn blocks FMA contraction,
// __fdiv_rn for the divide. gA identically zero (ADAPT_INC==0), elided.

#ifndef PFD
#define PFD 16   // prefetch depth (steps per register block)
#endif

__global__ __launch_bounds__(256, 1) void lif_scan(
    const float* __restrict__ g_exc,
    const float* __restrict__ g_inh,
    const float* __restrict__ noise,
    const float* __restrict__ v_th,
    const float* __restrict__ tau_ref,
    float* __restrict__ out_spk,   // d_out[0 .. T*N)
    float* __restrict__ out_mem,   // d_out[T*N .. 2*T*N)
    int N, int T,
    float cGE, float cGI, float cALPHA, float cSIGMA)
{
    const int n = blockIdx.x * blockDim.x + threadIdx.x;
    if (n >= N) return;

    const float vth = v_th[n];
    const float trf = tau_ref[n];

    float v = 0.0f, gE = 0.0f, gI = 0.0f, ref = 0.0f, ou = 0.0f;

    const float* __restrict__ pge = g_exc + n;
    const float* __restrict__ pgi = g_inh + n;
    const float* __restrict__ pz  = noise + n;

    // one simulation step (same op order as the passing R1/R2 kernels,
    // except decay now via f32 expf)
    auto step = [&](float ge_in, float gi_in, float z, int tt) {
        gE = __fadd_rn(__fmul_rn(gE, cGE), ge_in);
        gI = __fadd_rn(__fmul_rn(gI, cGI), gi_in);

        const float gt  = __fadd_rn(__fadd_rn(1.0f, gE), gI);
        const float num = __fadd_rn(__fmul_rn(gE, 3.0f), __fmul_rn(gI, -0.5f));
        const float vinf = __fdiv_rn(num, gt);

        const float darg = __fmul_rn(-0.05f, gt);
        const float decay = expf(darg);   // ocml f32 exp, <=1 ulp

        v = __fadd_rn(vinf, __fmul_rn(__fsub_rn(v, vinf), decay));

        ou = __fadd_rn(__fmul_rn(ou, cALPHA), __fmul_rn(cSIGMA, z));
        v = __fadd_rn(v, ou);

        const bool in_ref = (ref > 0.0f);
        if (in_ref) v = 0.0f;

        const bool spike = (v >= vth) && (!in_ref);
        if (spike) v = 0.0f;
        ref = spike ? trf : fmaxf(__fsub_rn(ref, 1.0f), 0.0f);

        const size_t off = (size_t)tt * (size_t)N + (size_t)n;
        __builtin_nontemporal_store(spike ? 1.0f : 0.0f, out_spk + off);
        __builtin_nontemporal_store(v, out_mem + off);
    };

    float Age[PFD], Agi[PFD], Az[PFD];
    float Bge[PFD], Bgi[PFD], Bz[PFD];

    // prime buffer A with steps 0..PFD-1
    #pragma unroll
    for (int i = 0; i < PFD; ++i) {
        const size_t off = (size_t)i * (size_t)N;
        Age[i] = pge[off]; Agi[i] = pgi[off]; Az[i] = pz[off];
    }

    // main loop: 2*PFD steps per iteration, ping-pong A/B register blocks
    // (T=512 is an exact multiple of 2*PFD=32; clamp is belt-and-braces)
    for (int t = 0; t < T; t += 2 * PFD) {
        #pragma unroll
        for (int i = 0; i < PFD; ++i) {
            int tp = t + PFD + i; tp = tp < T ? tp : T - 1;
            const size_t off = (size_t)tp * (size_t)N;
            Bge[i] = pge[off]; Bgi[i] = pgi[off]; Bz[i] = pz[off];
        }
        __builtin_amdgcn_sched_barrier(0);  // prefetch issued before compute
        #pragma unroll
        for (int i = 0; i < PFD; ++i)
            step(Age[i], Agi[i], Az[i], t + i);

        #pragma unroll
        for (int i = 0; i < PFD; ++i) {
            int tp = t + 2 * PFD + i; tp = tp < T ? tp : T - 1;
            const size_t off = (size_t)tp * (size_t)N;
            Age[i] = pge[off]; Agi[i] = pgi[off]; Az[i] = pz[off];
        }
        __builtin_amdgcn_sched_barrier(0);
        #pragma unroll
        for (int i = 0; i < PFD; ++i)
            step(Bge[i], Bgi[i], Bz[i], t + PFD + i);
    }
}

extern "C" void kernel_launch(void* const* d_in, const int* in_sizes, int n_in,
                              void* d_out, int out_size, void* d_ws, size_t ws_size,
                              hipStream_t stream) {
    const float* g_exc   = (const float*)d_in[0];
    const float* g_inh   = (const float*)d_in[1];
    const float* noise   = (const float*)d_in[2];
    const float* v_th    = (const float*)d_in[3];
    const float* tau_ref = (const float*)d_in[4];

    const int N = in_sizes[3];            // 65536
    const int T = in_sizes[0] / N;        // 512

    float* out_spk = (float*)d_out;
    float* out_mem = (float*)d_out + (size_t)T * (size_t)N;

    // Constants computed in double exactly as the Python reference does.
    const double ge_decay = exp(-1.0 / 5.0);
    const double gi_decay = exp(-1.0 / 10.0);
    const double ou_alpha = exp(-1.0 / 5.0);
    const double ou_sigma = 0.02 * sqrt(1.0 - ou_alpha * ou_alpha);

    const int block = 256;
    const int grid = (N + block - 1) / block;   // 256 blocks -> 1 block/CU
    lif_scan<<<grid, block, 0, stream>>>(
        g_exc, g_inh, noise, v_th, tau_ref, out_spk, out_mem,
        N, T,
        (float)ge_decay, (float)gi_decay, (float)ou_alpha, (float)ou_sigma);
}